// Round 1
// baseline (14.927 us; speedup 1.0000x reference)
//
#include <hip/hip_runtime.h>
#include <math.h>

// Analytic reduction of the "quantum" feature map:
//   product state + CRX(0)=identity  =>  <Z_q> = cos(a_q) * cos(b_q)
//   with a_q = x[3q mod 6], b_q = x[(3q+1) mod 6]
//   => qf[q] = cos(x0)cos(x1) for even q, cos(x3)cos(x4) for odd q.
// Then: out = tanh([x, qf] @ W1 + b1) @ W2 + b2.

constexpr int DIN = 6;
constexpr int NQ = 10;
constexpr int K = DIN + NQ;            // 16
constexpr int H = 256;
constexpr int THREADS = 256;
constexpr int PARTS = 4;               // threads cooperating per sample
constexpr int SPB = THREADS / PARTS;   // 64 samples per block
constexpr int HPER = H / PARTS;        // 64 hidden units per thread

__device__ __forceinline__ float fast_tanh(float x) {
    // tanh(x) = 1 - 2/(e^{2x}+1); safe at both tails (inf -> 1, 0 -> -1)
    return 1.0f - 2.0f / (__expf(2.0f * x) + 1.0f);
}

__global__ __launch_bounds__(THREADS) void qnn_fused_kernel(
    const float* __restrict__ x,    // [B, 6]
    const float* __restrict__ W1,   // [16, 256] row-major (k-major)
    const float* __restrict__ b1,   // [256]
    const float* __restrict__ W2,   // [256, 1]
    const float* __restrict__ b2,   // [1]
    float* __restrict__ out,        // [B, 1]
    int B)
{
    __shared__ float sW1[K * H];    // 16 KB
    __shared__ float sb1[H];
    __shared__ float sW2[H];
    __shared__ float sx[SPB * DIN]; // 1.5 KB

    const int t = threadIdx.x;

    // Stage weights: 4096/256 = 16 floats of W1 per thread, coalesced.
#pragma unroll
    for (int i = 0; i < (K * H) / THREADS; ++i)
        sW1[i * THREADS + t] = W1[i * THREADS + t];
    sb1[t] = b1[t];
    sW2[t] = W2[t];

    const int base = blockIdx.x * SPB;
    for (int i = t; i < SPB * DIN; i += THREADS) {
        const int idx = base * DIN + i;
        sx[i] = (idx < B * DIN) ? x[idx] : 0.0f;
    }
    __syncthreads();

    const int s = t >> 2;          // sample within block
    const int part = t & 3;        // which quarter of hidden units
    const int sample = base + s;

    // Build combined[16] in registers.
    float c[K];
#pragma unroll
    for (int k = 0; k < DIN; ++k) c[k] = sx[s * DIN + k];
    const float u = __cosf(c[0]) * __cosf(c[1]);
    const float v = __cosf(c[3]) * __cosf(c[4]);
#pragma unroll
    for (int q = 0; q < NQ; q += 2) { c[DIN + q] = u; c[DIN + q + 1] = v; }

    // Each thread: 64 hidden units, interleaved so the 4 parts of a sample
    // touch 4 consecutive LDS words (conflict-free broadcast within wave).
    float acc = 0.0f;
#pragma unroll 8
    for (int i = 0; i < HPER; ++i) {
        const int hh = (i << 2) | part;
        float sacc = sb1[hh];
#pragma unroll
        for (int k = 0; k < K; ++k)
            sacc = fmaf(c[k], sW1[k * H + hh], sacc);
        acc = fmaf(fast_tanh(sacc), sW2[hh], acc);
    }

    // Reduce the 4 partial sums (lanes t, t^1, t^2 within the wave).
    acc += __shfl_xor(acc, 1);
    acc += __shfl_xor(acc, 2);

    if (part == 0 && sample < B) out[sample] = acc + b2[0];
}

extern "C" void kernel_launch(void* const* d_in, const int* in_sizes, int n_in,
                              void* d_out, int out_size, void* d_ws, size_t ws_size,
                              hipStream_t stream) {
    const float* x  = (const float*)d_in[0];
    const float* W1 = (const float*)d_in[1];
    const float* b1 = (const float*)d_in[2];
    const float* W2 = (const float*)d_in[3];
    const float* b2 = (const float*)d_in[4];
    float* out = (float*)d_out;

    const int B = in_sizes[0] / DIN;            // 16384
    const int blocks = (B + SPB - 1) / SPB;     // 256
    qnn_fused_kernel<<<blocks, THREADS, 0, stream>>>(x, W1, b1, W2, b2, out, B);
}

// Round 2
// 10.097 us; speedup vs baseline: 1.4783x; 1.4783x over previous
//
#include <hip/hip_runtime.h>
#include <math.h>

// Analytic reduction of the "quantum" feature map:
//   product state + CRX(0)=identity  =>  <Z_q> = cos(a_q) * cos(b_q)
//   => qf[q] = cos(x0)cos(x1) (even q) or cos(x3)cos(x4) (odd q).
// Then: out = tanh([x, qf] @ W1 + b1) @ W2 + b2.
//
// Layout: lane = sample (64 samples per wave), wave w of 8 handles hidden
// units [32w, 32w+32). All weight indices are wave-uniform (readfirstlane'd
// wave id + unrolled loop constants) -> compiler issues scalar s_load's;
// weights fold into v_fmac as SGPR operands. No LDS in the hot loop.

constexpr int DIN = 6;
constexpr int NQ = 10;
constexpr int K = DIN + NQ;        // 16
constexpr int H = 256;
constexpr int WAVES = 8;
constexpr int TPB = WAVES * 64;    // 512 threads
constexpr int SPB = 64;            // samples per block (one per lane)
constexpr int HPW = H / WAVES;     // 32 hidden units per wave

__global__ __launch_bounds__(TPB) void qnn_fused_kernel(
    const float* __restrict__ x,    // [B, 6]
    const float* __restrict__ W1,   // [16, 256]
    const float* __restrict__ b1,   // [256]
    const float* __restrict__ W2,   // [256]
    const float* __restrict__ b2,   // [1]
    float* __restrict__ out,        // [B]
    int B)
{
    __shared__ float partial[WAVES][SPB];   // 2 KB

    const int lane = threadIdx.x & 63;
    const int wid  = __builtin_amdgcn_readfirstlane(threadIdx.x >> 6);
    const int sample = blockIdx.x * SPB + lane;

    // Per-lane features (24-byte rows are float2-aligned).
    float c[K];
    if (sample < B) {
        const float2* xp = (const float2*)(x + sample * DIN);
        const float2 a0 = xp[0], a1 = xp[1], a2 = xp[2];
        c[0] = a0.x; c[1] = a0.y; c[2] = a1.x;
        c[3] = a1.y; c[4] = a2.x; c[5] = a2.y;
    } else {
#pragma unroll
        for (int k = 0; k < DIN; ++k) c[k] = 0.0f;
    }
    const float u = __cosf(c[0]) * __cosf(c[1]);
    const float v = __cosf(c[3]) * __cosf(c[4]);
#pragma unroll
    for (int q = 0; q < NQ; q += 2) { c[DIN + q] = u; c[DIN + q + 1] = v; }

    // Hot loop: 32 hidden units per wave; all weight loads are scalar.
    const int hh0 = wid * HPW;
    float acc = 0.0f;
#pragma unroll
    for (int i = 0; i < HPW; ++i) {
        const int hh = hh0 + i;
        float s = b1[hh];
#pragma unroll
        for (int k = 0; k < K; ++k)
            s = fmaf(c[k], W1[k * H + hh], s);
        // tanh(s) = 1 - 2/(e^{2s}+1); rcp handles both tails correctly.
        const float e = __expf(2.0f * s);
        const float t = 1.0f - 2.0f * __builtin_amdgcn_rcpf(e + 1.0f);
        acc = fmaf(t, W2[hh], acc);
    }

    partial[wid][lane] = acc;
    __syncthreads();

    if (wid == 0) {
        float r = b2[0];
#pragma unroll
        for (int j = 0; j < WAVES; ++j) r += partial[j][lane];
        if (sample < B) out[sample] = r;   // coalesced 256B store per wave
    }
}

extern "C" void kernel_launch(void* const* d_in, const int* in_sizes, int n_in,
                              void* d_out, int out_size, void* d_ws, size_t ws_size,
                              hipStream_t stream) {
    const float* x  = (const float*)d_in[0];
    const float* W1 = (const float*)d_in[1];
    const float* b1 = (const float*)d_in[2];
    const float* W2 = (const float*)d_in[3];
    const float* b2 = (const float*)d_in[4];
    float* out = (float*)d_out;

    const int B = in_sizes[0] / DIN;              // 16384
    const int blocks = (B + SPB - 1) / SPB;       // 256
    qnn_fused_kernel<<<blocks, TPB, 0, stream>>>(x, W1, b1, W2, b2, out, B);
}

// Round 3
// 9.649 us; speedup vs baseline: 1.5469x; 1.0464x over previous
//
#include <hip/hip_runtime.h>
#include <math.h>

// Analytic reduction of the "quantum" feature map:
//   product state + CRX(0)=identity  =>  <Z_q> = cos(a_q) * cos(b_q)
//   => qf[q] = cos(x0)cos(x1) (even q) or cos(x3)cos(x4) (odd q).
// Then: out = tanh([x, qf] @ W1 + b1) @ W2 + b2.
//
// Layout: lane = sample (64 samples per block), 16 waves per block, wave w
// handles hidden units [16w, 16w+16). Weight indices are wave-uniform
// (readfirstlane'd wave id + unrolled constants) -> scalar s_loads that fold
// into v_fmac as SGPR operands; 16 waves/block = 4 waves/SIMD hides the
// s_load (L2 ~200cyc) and FMA-chain latency. No LDS in the hot loop.

constexpr int DIN = 6;
constexpr int NQ = 10;
constexpr int K = DIN + NQ;        // 16
constexpr int H = 256;
constexpr int WAVES = 16;
constexpr int TPB = WAVES * 64;    // 1024 threads
constexpr int SPB = 64;            // samples per block (one per lane)
constexpr int HPW = H / WAVES;     // 16 hidden units per wave

__global__ __launch_bounds__(TPB) void qnn_fused_kernel(
    const float* __restrict__ x,    // [B, 6]
    const float* __restrict__ W1,   // [16, 256]
    const float* __restrict__ b1,   // [256]
    const float* __restrict__ W2,   // [256]
    const float* __restrict__ b2,   // [1]
    float* __restrict__ out,        // [B]
    int B)
{
    __shared__ float partial[WAVES][SPB];   // 4 KB

    const int lane = threadIdx.x & 63;
    const int wid  = __builtin_amdgcn_readfirstlane(threadIdx.x >> 6);
    const int sample = blockIdx.x * SPB + lane;

    // Per-lane features (24-byte rows are float2-aligned).
    float c[K];
    if (sample < B) {
        const float2* xp = (const float2*)(x + sample * DIN);
        const float2 a0 = xp[0], a1 = xp[1], a2 = xp[2];
        c[0] = a0.x; c[1] = a0.y; c[2] = a1.x;
        c[3] = a1.y; c[4] = a2.x; c[5] = a2.y;
    } else {
#pragma unroll
        for (int k = 0; k < DIN; ++k) c[k] = 0.0f;
    }
    const float u = __cosf(c[0]) * __cosf(c[1]);
    const float v = __cosf(c[3]) * __cosf(c[4]);
#pragma unroll
    for (int q = 0; q < NQ; q += 2) { c[DIN + q] = u; c[DIN + q + 1] = v; }

    // Hot loop: 16 hidden units per wave; all weight loads are scalar.
    const int hh0 = wid * HPW;
    float acc = 0.0f;
#pragma unroll
    for (int i = 0; i < HPW; ++i) {
        const int hh = hh0 + i;
        float s = b1[hh];
#pragma unroll
        for (int k = 0; k < K; ++k)
            s = fmaf(c[k], W1[k * H + hh], s);
        // tanh(s) = 1 - 2/(e^{2s}+1); rcp handles both tails correctly.
        const float e = __expf(2.0f * s);
        const float t = 1.0f - 2.0f * __builtin_amdgcn_rcpf(e + 1.0f);
        acc = fmaf(t, W2[hh], acc);
    }

    partial[wid][lane] = acc;
    __syncthreads();

    if (wid == 0) {
        float r = b2[0];
#pragma unroll
        for (int j = 0; j < WAVES; ++j) r += partial[j][lane];
        if (sample < B) out[sample] = r;   // coalesced 256B store per wave
    }
}

extern "C" void kernel_launch(void* const* d_in, const int* in_sizes, int n_in,
                              void* d_out, int out_size, void* d_ws, size_t ws_size,
                              hipStream_t stream) {
    const float* x  = (const float*)d_in[0];
    const float* W1 = (const float*)d_in[1];
    const float* b1 = (const float*)d_in[2];
    const float* W2 = (const float*)d_in[3];
    const float* b2 = (const float*)d_in[4];
    float* out = (float*)d_out;

    const int B = in_sizes[0] / DIN;              // 16384
    const int blocks = (B + SPB - 1) / SPB;       // 256
    qnn_fused_kernel<<<blocks, TPB, 0, stream>>>(x, W1, b1, W2, b2, out, B);
}